// Round 4
// baseline (118.876 us; speedup 1.0000x reference)
//
#include <hip/hip_runtime.h>
#include <hip/hip_bf16.h>

// NT-Xent loss, N=4096, D=256, fp32 inputs, fp32 scalar output.
// loss = mean_i [ log( sum_{j != i} exp(2*cos(zn_i, zn_j)) ) - 2*cos(zn_i, zn_pair(i)) ]
//
// k1: normalize rows -> bf16 zn in ws, fp32 inv-norms, zero rowsum
// k2: symmetric Gram row-sums of exp, 16x16x32 bf16 MFMA, triangular 128x128 tiles.
//     v3 (resubmit; round-3 bench was a container infra failure, no data):
//     counted-vmcnt pipeline (T3/T4): whole 128-col tile staged into TWO
//     non-reused LDS buffers, all DMA issued up-front in pinned order
//     [D0 x8][A x16][D1 x8], consume behind s_waitcnt vmcnt(8)/vmcnt(0) +
//     s_barrier. NO full mid-kernel drains. (r0/r1/r2 post-mortem: three
//     different 2-phase structures all pinned at 43-45us with all pipes idle
//     == the m233 stage+vmcnt(0)+barrier critical-path overhead.)
// k3: per-row contrib = log(rowsum - exp(diag)) - pair_sim   (fp32-exact pair term)
// k4: reduce 8192 contribs -> d_out[0]

#define NROWS 8192
#define NHALF 4096
#define DDIM  256

typedef __bf16 bf16;
typedef __bf16 bf16x4 __attribute__((ext_vector_type(4)));
typedef __bf16 bf16x8 __attribute__((ext_vector_type(8)));
typedef float  f32x4  __attribute__((ext_vector_type(4)));

__constant__ const float kTwoLog2e = 2.8853900817779268f;  // 2*log2(e): exp(2x)=exp2(kTwoLog2e*x)
__constant__ const float kLn2      = 0.6931471805599453f;

__device__ __forceinline__ const float* zrow(const float* z1, const float* z2, int r) {
  return (r < NHALF) ? (z1 + (size_t)r * DDIM) : (z2 + (size_t)(r - NHALF) * DDIM);
}

// ---------------- k1: normalize ----------------
__global__ void k_normalize(const float* __restrict__ z1, const float* __restrict__ z2,
                            bf16* __restrict__ zn, float* __restrict__ invn,
                            float* __restrict__ rowsum) {
  const int wave = threadIdx.x >> 6, lane = threadIdx.x & 63;
  const int row = blockIdx.x * 4 + wave;
  const float* src = zrow(z1, z2, row);
  f32x4 v = *(const f32x4*)(src + lane * 4);
  float ss = v.x * v.x + v.y * v.y + v.z * v.z + v.w * v.w;
#pragma unroll
  for (int off = 1; off < 64; off <<= 1) ss += __shfl_xor(ss, off);
  const float inv = 1.0f / fmaxf(sqrtf(ss), 1e-8f);
  bf16x4 o;
  o.x = (bf16)(v.x * inv); o.y = (bf16)(v.y * inv);
  o.z = (bf16)(v.z * inv); o.w = (bf16)(v.w * inv);
  *(bf16x4*)(zn + (size_t)row * DDIM + lane * 4) = o;
  if (lane == 0) { invn[row] = inv; rowsum[row] = 0.0f; }
}

// ---------------- k2: symmetric Gram row-sums of exp ----------------
// 256 threads = 4 waves. Tile 128x128 (upper triangle incl. diagonal).
// Rows: wave owns 32 (s=2 x 16), K=256 in regs (a[2][8] = 64 VGPR).
// Cols: two 64-col halves, each in its OWN 32KB LDS buffer (no reuse -> no WAR
// barrier). XOR-swizzled SOURCE (rule #21), f(r) = r&15: read slot sl has
// sl&7 uniformly distributed over the wave -> even 32-bank spread on
// ds_read_b128 (theoretical-minimum LDS cycles).
#define BMG 128
#define NTILES 2080  // 64*65/2

typedef const __attribute__((address_space(1))) unsigned int* as1_u32p;
typedef __attribute__((address_space(3))) unsigned int* as3_u32p;

__device__ __forceinline__ void load_lds16(const void* g, void* l) {
  __builtin_amdgcn_global_load_lds((as1_u32p)g, (as3_u32p)l, 16, 0, 0);
}

__global__ __launch_bounds__(256, 2) void k_gram(const bf16* __restrict__ zn,
                                                 float* __restrict__ rowsum) {
  __shared__ __align__(16) unsigned char ldsb[2][64 * 512];  // 2 x 32KB, never reused
  const int tid  = threadIdx.x;
  const int wave = tid >> 6, lane = tid & 63;
  const int quad = lane >> 4, l15 = lane & 15;

  // ---- triangular tile decode: blockIdx.x -> (I, J), I <= J, I,J in [0,64) ----
  const int kb = blockIdx.x;
  int I = (int)((129.0f - sqrtf((float)(16641 - 8 * kb))) * 0.5f);
  while ((I + 1) * (129 - (I + 1)) / 2 <= kb) ++I;   // float-slop guards (bounded)
  while (I * (129 - I) / 2 > kb) --I;
  const int J = I + (kb - I * (129 - I) / 2);
  const bool diag = (I == J);
  const int R0 = I * BMG + wave * 32;   // this wave's first A row
  const int C0 = J * BMG;               // tile's first col

  // ---- VMEM issue order (per wave): [DMA half0 x8] [A-loads x16] [DMA half1 x8] ----
  // Counted waits below rely on this exact order; sched_barrier pins it.
  {
    const unsigned char* s0 = (const unsigned char*)(zn + (size_t)C0 * DDIM);
#pragma unroll
    for (int j = 0; j < 8; ++j) {
      const int p = (wave * 8 + j) * 64 + lane;  // 16B-chunk position 0..2047
      const int r = p >> 5;                      // staged col-row 0..63
      const int q = (p & 31) ^ (r & 15);         // swizzle inverse on SOURCE
      load_lds16(s0 + r * 512 + q * 16, &ldsb[0][(wave * 8 + j) * 1024]);
    }
  }

  bf16x8 a[2][8];
#pragma unroll
  for (int s = 0; s < 2; ++s) {
    const bf16x8* ap = (const bf16x8*)(zn + (size_t)(R0 + s * 16 + l15) * DDIM);
#pragma unroll
    for (int kk = 0; kk < 8; ++kk) a[s][kk] = ap[kk * 4 + quad];
  }

  {
    const unsigned char* s1 = (const unsigned char*)(zn + (size_t)(C0 + 64) * DDIM);
#pragma unroll
    for (int j = 0; j < 8; ++j) {
      const int p = (wave * 8 + j) * 64 + lane;
      const int r = p >> 5;
      const int q = (p & 31) ^ (r & 15);
      load_lds16(s1 + r * 512 + q * 16, &ldsb[1][(wave * 8 + j) * 1024]);
    }
  }
  __builtin_amdgcn_sched_barrier(0);  // pin issue order above

  float sum[2][4] = {{0.f, 0.f, 0.f, 0.f}, {0.f, 0.f, 0.f, 0.f}};
  float csum[2][4];
  const f32x4 zero4 = {0.f, 0.f, 0.f, 0.f};

#pragma unroll
  for (int h = 0; h < 2; ++h) {
    // Counted wait: h=0 -> drain [D0 + A], leave D1 (8) in flight; h=1 -> drain all.
    if (h == 0) {
      asm volatile("s_waitcnt vmcnt(8)" ::: "memory");
    } else {
      asm volatile("s_waitcnt vmcnt(0)" ::: "memory");
    }
    __builtin_amdgcn_s_barrier();        // all waves' DMA for buf h complete
    __builtin_amdgcn_sched_barrier(0);   // no ds_read hoisting above the barrier

    const unsigned char* bp = ldsb[h];

    f32x4 acc[2][4];
#pragma unroll
    for (int s = 0; s < 2; ++s)
#pragma unroll
      for (int cs = 0; cs < 4; ++cs) acc[s][cs] = zero4;

    __builtin_amdgcn_s_setprio(1);
#pragma unroll
    for (int kk = 0; kk < 8; ++kk) {
      bf16x8 b[4];
#pragma unroll
      for (int cs = 0; cs < 4; ++cs) {
        const int rb = cs * 16 + l15;                // staged col-row 0..63
        const int sl = (kk * 4 + quad) ^ (rb & 15);  // swizzled chunk slot
        b[cs] = *(const bf16x8*)(bp + rb * 512 + sl * 16);
      }
#pragma unroll
      for (int s = 0; s < 2; ++s)
#pragma unroll
        for (int cs = 0; cs < 4; ++cs)
          acc[s][cs] =
              __builtin_amdgcn_mfma_f32_16x16x32_bf16(a[s][kk], b[cs], acc[s][cs], 0, 0, 0);
    }
    __builtin_amdgcn_s_setprio(0);

#pragma unroll
    for (int cs = 0; cs < 4; ++cs) {
      float c = 0.f;
#pragma unroll
      for (int s = 0; s < 2; ++s)
#pragma unroll
        for (int r = 0; r < 4; ++r) {
          const float e = __builtin_amdgcn_exp2f(acc[s][cs][r] * kTwoLog2e);
          sum[s][r] += e;
          c += e;
        }
      csum[h][cs] = c;
    }
  }

  // ---- row-sums: C/D layout (m89): row = quad*4 + r, col = l15 -> reduce over l15 ----
#pragma unroll
  for (int s = 0; s < 2; ++s)
#pragma unroll
    for (int r = 0; r < 4; ++r) {
      float v = sum[s][r];
      v += __shfl_xor(v, 1); v += __shfl_xor(v, 2);
      v += __shfl_xor(v, 4); v += __shfl_xor(v, 8);
      if (l15 == 0) atomicAdd(&rowsum[R0 + s * 16 + quad * 4 + r], v);
    }

  // ---- col-sums (off-diag tiles only): reduce over quad lanes (xor 16, 32) ----
  if (!diag) {
#pragma unroll
    for (int h = 0; h < 2; ++h)
#pragma unroll
      for (int cs = 0; cs < 4; ++cs) {
        float v = csum[h][cs];
        v += __shfl_xor(v, 16); v += __shfl_xor(v, 32);
        if (quad == 0) atomicAdd(&rowsum[C0 + h * 64 + cs * 16 + l15], v);
      }
  }
}

// ---------------- k3: per-row contribution ----------------
__global__ void k_finalize(const float* __restrict__ z1, const float* __restrict__ z2,
                           const bf16* __restrict__ zn, const float* __restrict__ invn,
                           const float* __restrict__ rowsum, float* __restrict__ contrib) {
  const int wave = threadIdx.x >> 6, lane = threadIdx.x & 63;
  const int row = blockIdx.x * 4 + wave;
  const int pr = (row < NHALF) ? row + NHALF : row - NHALF;

  f32x4 a4 = *(const f32x4*)(zrow(z1, z2, row) + lane * 4);
  f32x4 b4 = *(const f32x4*)(zrow(z1, z2, pr) + lane * 4);
  bf16x4 nb = *(const bf16x4*)(zn + (size_t)row * DDIM + lane * 4);

  float pd = a4.x * b4.x + a4.y * b4.y + a4.z * b4.z + a4.w * b4.w;
  float f0 = (float)nb.x, f1 = (float)nb.y, f2 = (float)nb.z, f3 = (float)nb.w;
  float nd = f0 * f0 + f1 * f1 + f2 * f2 + f3 * f3;
#pragma unroll
  for (int off = 1; off < 64; off <<= 1) {
    pd += __shfl_xor(pd, off);
    nd += __shfl_xor(nd, off);
  }
  if (lane == 0) {
    const float p = 2.0f * pd * invn[row] * invn[pr];               // exact fp32 pair sim
    const float dexp = __builtin_amdgcn_exp2f(kTwoLog2e * nd);      // the GEMM's diagonal term
    const float lse = __builtin_amdgcn_logf(rowsum[row] - dexp) * kLn2;
    contrib[row] = lse - p;
  }
}

// ---------------- k4: reduce 8192 contribs ----------------
__global__ void k_reduce(const float* __restrict__ contrib, float* __restrict__ out) {
  const int wave = threadIdx.x >> 6, lane = threadIdx.x & 63;
  float acc = 0.0f;
  for (int i = threadIdx.x; i < NROWS; i += 256) acc += contrib[i];
#pragma unroll
  for (int off = 1; off < 64; off <<= 1) acc += __shfl_xor(acc, off);
  __shared__ float wsum[4];
  if (lane == 0) wsum[wave] = acc;
  __syncthreads();
  if (threadIdx.x == 0)
    out[0] = (wsum[0] + wsum[1] + wsum[2] + wsum[3]) * (1.0f / (float)NROWS);
}

extern "C" void kernel_launch(void* const* d_in, const int* in_sizes, int n_in,
                              void* d_out, int out_size, void* d_ws, size_t ws_size,
                              hipStream_t stream) {
  const float* z1 = (const float*)d_in[0];
  const float* z2 = (const float*)d_in[1];
  unsigned char* ws = (unsigned char*)d_ws;

  // ws layout: zn bf16 [8192*256] (4 MB) | invn f32[8192] | rowsum f32[8192] | contrib f32[8192]
  bf16* zn = (bf16*)ws;
  float* invn = (float*)(ws + (size_t)NROWS * DDIM * sizeof(bf16));
  float* rowsum = invn + NROWS;
  float* contrib = rowsum + NROWS;

  hipLaunchKernelGGL(k_normalize, dim3(NROWS / 4), dim3(256), 0, stream, z1, z2, zn, invn, rowsum);
  hipLaunchKernelGGL(k_gram, dim3(NTILES), dim3(256), 0, stream, zn, rowsum);
  hipLaunchKernelGGL(k_finalize, dim3(NROWS / 4), dim3(256), 0, stream, z1, z2, zn, invn, rowsum,
                     contrib);
  hipLaunchKernelGGL(k_reduce, dim3(1), dim3(256), 0, stream, contrib, (float*)d_out);
}

// Round 5
// 117.044 us; speedup vs baseline: 1.0157x; 1.0157x over previous
//
#include <hip/hip_runtime.h>
#include <hip/hip_bf16.h>

// NT-Xent loss, N=4096, D=256, fp32 inputs, fp32 scalar output.
// loss = mean_i [ log( sum_{j != i} exp(2*cos(zn_i, zn_j)) ) - 2*cos(zn_i, zn_pair(i)) ]
//
// k1: normalize rows -> bf16 zn, fp32 inv-norms, zero rowsum, zero out[0]
// k2 (v5): symmetric Gram row-sums of exp via CIRCULANT decomposition.
//     r4 post-mortem: 4 schedules all 43-48us, blocks 14Kcy each vs 4Kcy work,
//     occupancy 1.3 blocks/CU -> pure latency in short blocks. v5: 512 blocks
//     (2/CU), each owns 128 rows (A in regs, loaded ONCE) x 512-640 cols via
//     8-10 iter rolling DMA pipeline (counted vmcnt(8), double buffer).
// k3: per-row contrib + fused block-reduce -> atomicAdd into out[0]
//     (k_reduce launch eliminated; k1 zeroes out[0], stream order guarantees).

#define NROWS 8192
#define NHALF 4096
#define DDIM  256

typedef __bf16 bf16;
typedef __bf16 bf16x4 __attribute__((ext_vector_type(4)));
typedef __bf16 bf16x8 __attribute__((ext_vector_type(8)));
typedef float  f32x4  __attribute__((ext_vector_type(4)));

__constant__ const float kTwoLog2e = 2.8853900817779268f;  // 2*log2(e): exp(2x)=exp2(kTwoLog2e*x)
__constant__ const float kLn2      = 0.6931471805599453f;

__device__ __forceinline__ const float* zrow(const float* z1, const float* z2, int r) {
  return (r < NHALF) ? (z1 + (size_t)r * DDIM) : (z2 + (size_t)(r - NHALF) * DDIM);
}

// ---------------- k1: normalize ----------------
__global__ void k_normalize(const float* __restrict__ z1, const float* __restrict__ z2,
                            bf16* __restrict__ zn, float* __restrict__ invn,
                            float* __restrict__ rowsum, float* __restrict__ out) {
  const int wave = threadIdx.x >> 6, lane = threadIdx.x & 63;
  const int row = blockIdx.x * 4 + wave;
  const float* src = zrow(z1, z2, row);
  f32x4 v = *(const f32x4*)(src + lane * 4);
  float ss = v.x * v.x + v.y * v.y + v.z * v.z + v.w * v.w;
#pragma unroll
  for (int off = 1; off < 64; off <<= 1) ss += __shfl_xor(ss, off);
  const float inv = 1.0f / fmaxf(sqrtf(ss), 1e-8f);
  bf16x4 o;
  o.x = (bf16)(v.x * inv); o.y = (bf16)(v.y * inv);
  o.z = (bf16)(v.z * inv); o.w = (bf16)(v.w * inv);
  *(bf16x4*)(zn + (size_t)row * DDIM + lane * 4) = o;
  if (lane == 0) { invn[row] = inv; rowsum[row] = 0.0f; }
  if (blockIdx.x == 0 && threadIdx.x == 0) out[0] = 0.0f;
}

// ---------------- k2: symmetric Gram row-sums of exp (circulant) ----------------
// Block (I, chunk): I in [0,64) row-tile of 128; chunk in [0,8) covers d-values
// {4c..4c+3} (+d=32 for chunk7 when I<32). Col-tile J = (I+d)&63; each 128-col
// J-tile = 2 LDS-iters of 64 cols. d=0 tile: row-sums only. Off-diag: rows AND
// cols (col-sum = transposed tile's row-sum). Coverage: d in [1,31] once from
// b=I; d=32 once via I<32; complete.
// Pipeline: rolling 2-buffer DMA, issue order [D(0)][A x16][D(1)] then D(t+2)
// at end of iter t. Wait vmcnt(8) per iter (col-atomics precede D(t+2) in FIFO
// order so the count remains sound), vmcnt(0) on last.
#define NBLK 512

typedef const __attribute__((address_space(1))) unsigned int* as1_u32p;
typedef __attribute__((address_space(3))) unsigned int* as3_u32p;

__device__ __forceinline__ void load_lds16(const void* g, void* l) {
  __builtin_amdgcn_global_lo\
ad_lds((as1_u32p)g, (as3_u32p)l, 16, 0, 0);
}

__global__ __launch_bounds__(256, 2) void k_gram(const bf16* __restrict__ zn,
                                                 float* __restrict__ rowsum) {
  __shared__ __align__(16) unsigned char ldsb[2][64 * 512];  // 2 x 32KB rolling
  const int tid  = threadIdx.x;
  const int wave = tid >> 6, lane = tid & 63;
  const int quad = lane >> 4, l15 = lane & 15;

  const int I      = blockIdx.x >> 3;   // row-tile [0,64)
  const int chunk  = blockIdx.x & 7;    // d-chunk [0,8)
  const int base_d = chunk * 4;
  const int n      = (chunk == 7 && I < 32) ? 10 : 8;  // 64-col LDS-iters
  const int R0     = I * 128 + wave * 32;

  // col base of LDS-iter t
  auto cbase = [&](int t) -> int {
    const int d = base_d + (t >> 1);
    const int J = (I + d) & 63;
    return J * 128 + (t & 1) * 64;
  };
  // DMA tile t into buffer b: 64 cols x 512B, linear LDS dest, swizzled source
  auto issue_dma = [&](int t, int b) {
    const unsigned char* s = (const unsigned char*)(zn + (size_t)cbase(t) * DDIM);
#pragma unroll
    for (int j = 0; j < 8; ++j) {
      const int p = (wave * 8 + j) * 64 + lane;  // 16B-chunk position 0..2047
      const int r = p >> 5;                      // staged col-row 0..63
      const int q = (p & 31) ^ (r & 15);         // swizzle inverse on SOURCE
      load_lds16(s + r * 512 + q * 16, &ldsb[b][(wave * 8 + j) * 1024]);
    }
  };

  // ---- pinned VMEM issue order: [D(0) x8] [A x16] [D(1) x8] ----
  issue_dma(0, 0);
  __builtin_amdgcn_sched_barrier(0);

  bf16x8 a[2][8];
#pragma unroll
  for (int s = 0; s < 2; ++s) {
    const bf16x8* ap = (const bf16x8*)(zn + (size_t)(R0 + s * 16 + l15) * DDIM);
#pragma unroll
    for (int kk = 0; kk < 8; ++kk) a[s][kk] = ap[kk * 4 + quad];
  }
  __builtin_amdgcn_sched_barrier(0);

  issue_dma(1, 1);
  __builtin_amdgcn_sched_barrier(0);

  float sum[2][4] = {{0.f, 0.f, 0.f, 0.f}, {0.f, 0.f, 0.f, 0.f}};
  const f32x4 zero4 = {0.f, 0.f, 0.f, 0.f};

  for (int t = 0; t < n; ++t) {
    // Counted wait: leaves D(t+1)'s 8 DMAs in flight (FIFO retire covers
    // earlier col-atomics too); last iter drains all.
    if (t == n - 1) asm volatile("s_waitcnt vmcnt(0)" ::: "memory");
    else            asm volatile("s_waitcnt vmcnt(8)" ::: "memory");
    __builtin_amdgcn_s_barrier();        // all waves' DMA for tile t complete
    __builtin_amdgcn_sched_barrier(0);   // no ds_read hoisting above barrier

    const unsigned char* bp = ldsb[t & 1];

    f32x4 acc[2][4];
#pragma unroll
    for (int s = 0; s < 2; ++s)
#pragma unroll
      for (int cs = 0; cs < 4; ++cs) acc[s][cs] = zero4;

    __builtin_amdgcn_s_setprio(1);
#pragma unroll
    for (int kk = 0; kk < 8; ++kk) {
      bf16x8 b[4];
#pragma unroll
      for (int cs = 0; cs < 4; ++cs) {
        const int rb = cs * 16 + l15;                // staged col-row 0..63
        const int sl = (kk * 4 + quad) ^ (rb & 15);  // swizzled chunk slot
        b[cs] = *(const bf16x8*)(bp + rb * 512 + sl * 16);
      }
#pragma unroll
      for (int s = 0; s < 2; ++s)
#pragma unroll
        for (int cs = 0; cs < 4; ++cs)
          acc[s][cs] =
              __builtin_amdgcn_mfma_f32_16x16x32_bf16(a[s][kk], b[cs], acc[s][cs], 0, 0, 0);
    }
    __builtin_amdgcn_s_setprio(0);

    // exp + row accumulation + per-iter col atomics (off-diag only)
    const bool dg = (chunk == 0 && t < 2);  // d==0 diagonal tile
    const int cb = cbase(t);
#pragma unroll
    for (int cs = 0; cs < 4; ++cs) {
      float c = 0.f;
#pragma unroll
      for (int s = 0; s < 2; ++s)
#pragma unroll
        for (int r = 0; r < 4; ++r) {
          const float e = __builtin_amdgcn_exp2f(acc[s][cs][r] * kTwoLog2e);
          sum[s][r] += e;
          c += e;
        }
      if (!dg) {
        c += __shfl_xor(c, 16); c += __shfl_xor(c, 32);
        if (quad == 0) atomicAdd(&rowsum[cb + cs * 16 + l15], c);
      }
    }

    __builtin_amdgcn_s_barrier();        // all waves done READING tile t
    __builtin_amdgcn_sched_barrier(0);
    if (t + 2 < n) {
      issue_dma(t + 2, t & 1);           // overwrite just-freed buffer
      __builtin_amdgcn_sched_barrier(0);
    }
  }

  // ---- row-sums: C/D layout (m89): row = quad*4 + r, col = l15 ----
#pragma unroll
  for (int s = 0; s < 2; ++s)
#pragma unroll
    for (int r = 0; r < 4; ++r) {
      float v = sum[s][r];
      v += __shfl_xor(v, 1); v += __shfl_xor(v, 2);
      v += __shfl_xor(v, 4); v += __shfl_xor(v, 8);
      if (l15 == 0) atomicAdd(&rowsum[R0 + s * 16 + quad * 4 + r], v);
    }
}

// ---------------- k3: per-row contribution + fused final reduce ----------------
__global__ void k_finalize(const float* __restrict__ z1, const float* __restrict__ z2,
                           const bf16* __restrict__ zn, const float* __restrict__ invn,
                           const float* __restrict__ rowsum, float* __restrict__ out) {
  const int wave = threadIdx.x >> 6, lane = threadIdx.x & 63;
  const int row = blockIdx.x * 4 + wave;
  const int pr = (row < NHALF) ? row + NHALF : row - NHALF;

  f32x4 a4 = *(const f32x4*)(zrow(z1, z2, row) + lane * 4);
  f32x4 b4 = *(const f32x4*)(zrow(z1, z2, pr) + lane * 4);
  bf16x4 nb = *(const bf16x4*)(zn + (size_t)row * DDIM + lane * 4);

  float pd = a4.x * b4.x + a4.y * b4.y + a4.z * b4.z + a4.w * b4.w;
  float f0 = (float)nb.x, f1 = (float)nb.y, f2 = (float)nb.z, f3 = (float)nb.w;
  float nd = f0 * f0 + f1 * f1 + f2 * f2 + f3 * f3;
#pragma unroll
  for (int off = 1; off < 64; off <<= 1) {
    pd += __shfl_xor(pd, off);
    nd += __shfl_xor(nd, off);
  }
  __shared__ float wsum[4];
  if (lane == 0) {
    const float p = 2.0f * pd * invn[row] * invn[pr];               // exact fp32 pair sim
    const float dexp = __builtin_amdgcn_exp2f(kTwoLog2e * nd);      // the GEMM's diagonal term
    const float lse = __builtin_amdgcn_logf(rowsum[row] - dexp) * kLn2;
    wsum[wave] = lse - p;
  }
  __syncthreads();
  if (threadIdx.x == 0)
    atomicAdd(out, (wsum[0] + wsum[1] + wsum[2] + wsum[3]) * (1.0f / (float)NROWS));
}

extern "C" void kernel_launch(void* const* d_in, const int* in_sizes, int n_in,
                              void* d_out, int out_size, void* d_ws, size_t ws_size,
                              hipStream_t stream) {
  const float* z1 = (const float*)d_in[0];
  const float* z2 = (const float*)d_in[1];
  unsigned char* ws = (unsigned char*)d_ws;

  // ws layout: zn bf16 [8192*256] (4 MB) | invn f32[8192] | rowsum f32[8192]
  bf16* zn = (bf16*)ws;
  float* invn = (float*)(ws + (size_t)NROWS * DDIM * sizeof(bf16));
  float* rowsum = invn + NROWS;
  float* out = (float*)d_out;

  hipLaunchKernelGGL(k_normalize, dim3(NROWS / 4), dim3(256), 0, stream, z1, z2, zn, invn, rowsum,
                     out);
  hipLaunchKernelGGL(k_gram, dim3(NBLK), dim3(256), 0, stream, zn, rowsum);
  hipLaunchKernelGGL(k_finalize, dim3(NROWS / 4), dim3(256), 0, stream, z1, z2, zn, invn, rowsum,
                     out);
}